// Round 4
// baseline (4906.062 us; speedup 1.0000x reference)
//
#include <hip/hip_runtime.h>

typedef _Float16 f16;
typedef _Float16 f16x8 __attribute__((ext_vector_type(8)));
typedef float f32x4 __attribute__((ext_vector_type(4)));

#define MFMA16(a, b, c) __builtin_amdgcn_mfma_f32_16x16x32_f16((a), (b), (c), 0, 0, 0)

__device__ __forceinline__ float sigmoidf_(float x) { return 1.f / (1.f + __expf(-x)); }
__device__ __forceinline__ float tanhf_(float x) { return 1.f - 2.f / (__expf(2.f * x) + 1.f); }

// ---------------- workspace layout (bytes) ----------------
// pk f16 element offsets: inW 0 | e0 16384 | e1 344064 | d0i 868352 | d0h 933888 | d1 950272 | out 983040
#define BIAS_OFF   1998848   // 2560 floats
#define FLAGS_OFF  2009088   // 12800 ints: flags0[64*100], flags1[64*100]
#define H0X_OFF    2060288   // [64][100][2][64][8] f16 = 13,107,200 B  (dead after enc0)
#define HX1_OFF    2060288   // [64][4][8][64][8] f16 = 2 MB   (overlaps dead h0x)
#define ZB_OFF     4157440   // [64][8][64][8] f16 = 512 KB    (within dead h0x, after hx1)
#define H1X_OFF    15167488  // [64][100][8][64][8] f16 = 52,428,800 B
// end 67,596,288 B

__global__ __launch_bounds__(256) void init_flags(int* f) {
    int i = blockIdx.x * 256 + threadIdx.x;
    if (i < 12800) f[i] = 0;
}

__global__ __launch_bounds__(256) void pack_kernel(
    const float* inW,
    const float* e0i, const float* e0h, const float* e1i, const float* e1h,
    const float* d0i, const float* d0h, const float* d1i, const float* d1h,
    const float* outW,
    const float* eb0i, const float* eb0h, const float* eb1i, const float* eb1h,
    const float* db0i, const float* db0h, const float* db1i, const float* db1h,
    f16* pk, float* bias_ws)
{
    int t = blockIdx.x * 256 + threadIdx.x;
    if (t < 124928) {
        int g = t; int KT, ka, kb; const float* A; const float* B; long doff;
        if (g < 2048)        {              KT = 8;  ka = 256; kb = 0;   A = inW;  B = nullptr; doff = 0; }
        else if (g < 43008)  { g -= 2048;   KT = 10; ka = 64;  kb = 256; A = e0i;  B = e0h;     doff = 16384; }
        else if (g < 108544) { g -= 43008;  KT = 16; ka = 256; kb = 256; A = e1i;  B = e1h;     doff = 344064; }
        else if (g < 116736) { g -= 108544; KT = 8;  ka = 256; kb = 0;   A = d0i;  B = nullptr; doff = 868352; }
        else if (g < 118784) { g -= 116736; KT = 2;  ka = 64;  kb = 0;   A = d0h;  B = nullptr; doff = 933888; }
        else if (g < 122880) { g -= 118784; KT = 4;  ka = 64;  kb = 64;  A = d1i;  B = d1h;     doff = 950272; }
        else                 { g -= 122880; KT = 2;  ka = 64;  kb = 0;   A = outW; B = nullptr; doff = 983040; }
        int lane = g & 63; int gk = g >> 6;
        int kt = gk % KT;  int nt = gk / KT;
        int n  = nt * 16 + (lane & 15);
        int k0 = kt * 32 + (lane >> 4) * 8;
        f16x8 v;
        #pragma unroll
        for (int j = 0; j < 8; ++j) {
            int k = k0 + j;
            float s = (k < ka) ? A[(long)n * ka + k] : B[(long)n * kb + (k - ka)];
            v[j] = (f16)s;
        }
        *(f16x8*)(pk + doff + (long)g * 8) = v;
    } else {
        int i = t - 124928;
        if (i < 1024)      bias_ws[i] = eb0i[i] + eb0h[i];
        else if (i < 2048) bias_ws[i] = eb1i[i - 1024] + eb1h[i - 1024];
        else if (i < 2304) bias_ws[i] = db0i[i - 2048] + db0h[i - 2048];
        else if (i < 2560) bias_ws[i] = db1i[i - 2304] + db1h[i - 2304];
    }
}

// Input projection, writes h0 in A-fragment layout h0x[c][t][kt][lane][8].
__global__ __launch_bounds__(256) void inproj_kernel(
    const float* __restrict__ x, const f16* __restrict__ pkInW,
    const float* __restrict__ in_b, f16* __restrict__ h0x)
{
    int bid = blockIdx.x;
    int c = bid / 100, t = bid % 100;
    int tid = threadIdx.x;
    int l = tid & 63, w = tid >> 6;
    int p = l & 15, q = l >> 4;
    f32x4 acc = {0.f, 0.f, 0.f, 0.f};
    const float* xrow = x + ((long)(16 * c + p) * 100 + t) * 256 + q * 8;
    const f16x8* bp = (const f16x8*)pkInW + w * 8 * 64 + l;
    #pragma unroll
    for (int kt = 0; kt < 8; ++kt) {
        const float4* xa = (const float4*)(xrow + kt * 32);
        float4 x0 = xa[0], x1 = xa[1];
        f16x8 a = {(f16)x0.x, (f16)x0.y, (f16)x0.z, (f16)x0.w,
                   (f16)x1.x, (f16)x1.y, (f16)x1.z, (f16)x1.w};
        acc = MFMA16(a, bp[kt * 64], acc);
    }
    int n = w * 16 + p;
    float bn = in_b[n];
    f16* hw = h0x + ((long)(c * 100 + t) * 2 + (n >> 5)) * 512 + (((n >> 3) & 3) * 16) * 8 + (n & 7);
    #pragma unroll
    for (int r = 0; r < 4; ++r) {
        float v = acc[r] + bn;
        v = v > 0.f ? v : 0.f;
        hw[(q * 4 + r) * 8] = (f16)v;
    }
}

// Weight-stationary persistent LSTM layer. REGULAR launch, grid 256 = 64 clusters x 4
// slice-blocks; __launch_bounds__(256,1) guarantees 1 block/CU schedulability -> all 256
// blocks co-resident on 256 CUs; no cross-cluster circular wait -> spin-flags safe.
// Cross-block exchange via agent-scope (sc1) atomics; flags provide ordering.
template <int KTX, int TSLOT, bool WZ>
__global__ __launch_bounds__(256, 1) void lstm_enc_reg(
    const f16* __restrict__ xfrag,   // [64][100][KTX][64][8]
    const f16* __restrict__ pkW,     // [64 nt][KTX+8][64][8]
    const float* __restrict__ bias,  // [1024]
    f16* __restrict__ hx,            // [64][TSLOT][8][64][8]
    int* __restrict__ flags,         // [64][100]
    f16* __restrict__ zbuf)          // [64][8][64][8] (WZ: h_99 handoff)
{
    constexpr int KT = KTX + 8;
    int tid = threadIdx.x;
    int l = tid & 63, w = tid >> 6;
    int p = l & 15, q = l >> 4;
    int c = blockIdx.x & 63;
    int s = blockIdx.x >> 6;

    // register-resident weight fragments
    f16x8 wx[4][KTX], wh[4][8];
    #pragma unroll
    for (int g = 0; g < 4; ++g) {
        const f16x8* wp = (const f16x8*)pkW + (long)((g * 16 + s * 4 + w) * KT) * 64 + l;
        #pragma unroll
        for (int kt = 0; kt < KTX; ++kt) wx[g][kt] = wp[kt * 64];
        #pragma unroll
        for (int kt = 0; kt < 8; ++kt)  wh[g][kt] = wp[(KTX + kt) * 64];
    }
    float bs[4];
    #pragma unroll
    for (int g = 0; g < 4; ++g) bs[g] = bias[g * 256 + s * 64 + w * 16 + p];
    float cst[4] = {0.f, 0.f, 0.f, 0.f};

    // write coords into exchange layout (j = 64s + 16w + p)
    int ktw = 2 * s + (w >> 1);
    int hiw = (2 * w + (p >> 3)) & 3;
    int jw  = p & 7;
    short* hxs = (short*)hx;
    int*   hxi = (int*)hx;
    int*   flc = flags + c * 100;

    for (int t = 0; t < 100; ++t) {
        f32x4 acc[4];
        #pragma unroll
        for (int g = 0; g < 4; ++g) acc[g] = (f32x4){0.f, 0.f, 0.f, 0.f};

        // x-part (prior-kernel data: plain loads fine)
        const f16x8* xp = (const f16x8*)xfrag + (long)((c * 100 + t) * KTX) * 64 + l;
        f16x8 ax[KTX];
        #pragma unroll
        for (int kt = 0; kt < KTX; ++kt) ax[kt] = xp[kt * 64];
        #pragma unroll
        for (int kt = 0; kt < KTX; ++kt)
            #pragma unroll
            for (int g = 0; g < 4; ++g)
                acc[g] = MFMA16(ax[kt], wx[g][kt], acc[g]);

        // h-part: wait for h_{t-1}, read via sc1 dword atomics
        if (t > 0) {
            int* fp = flc + (t - 1);
            while (__hip_atomic_load(fp, __ATOMIC_ACQUIRE, __HIP_MEMORY_SCOPE_AGENT) < 16)
                __builtin_amdgcn_s_sleep(1);
            int slot = (t - 1) % TSLOT;
            int* tb = hxi + (long)((c * TSLOT + slot) * 8) * 256 + l * 4;
            f16x8 ah[8];
            #pragma unroll
            for (int kt = 0; kt < 8; ++kt) {
                union { int i[4]; f16x8 v; } u;
                int* gp = tb + kt * 256;
                u.i[0] = __hip_atomic_load(gp + 0, __ATOMIC_RELAXED, __HIP_MEMORY_SCOPE_AGENT);
                u.i[1] = __hip_atomic_load(gp + 1, __ATOMIC_RELAXED, __HIP_MEMORY_SCOPE_AGENT);
                u.i[2] = __hip_atomic_load(gp + 2, __ATOMIC_RELAXED, __HIP_MEMORY_SCOPE_AGENT);
                u.i[3] = __hip_atomic_load(gp + 3, __ATOMIC_RELAXED, __HIP_MEMORY_SCOPE_AGENT);
                ah[kt] = u.v;
            }
            #pragma unroll
            for (int kt = 0; kt < 8; ++kt)
                #pragma unroll
                for (int g = 0; g < 4; ++g)
                    acc[g] = MFMA16(ah[kt], wh[g][kt], acc[g]);
        }

        // pointwise (in-lane) + sc1 2B stores into exchange layout
        int slot = t % TSLOT;
        short* hw = hxs + (long)((c * TSLOT + slot) * 8 + ktw) * 512 + hiw * 128 + jw;
        f16* zw = zbuf + (long)(c * 8 + ktw) * 512 + hiw * 128 + jw;
        #pragma unroll
        for (int r = 0; r < 4; ++r) {
            float iv = sigmoidf_(acc[0][r] + bs[0]);
            float fv = sigmoidf_(acc[1][r] + bs[1]);
            float gv = tanhf_(acc[2][r] + bs[2]);
            float ov = sigmoidf_(acc[3][r] + bs[3]);
            float cv = fv * cst[r] + iv * gv;
            cst[r] = cv;
            float hv = ov * tanhf_(cv);
            union { f16 h; short s2; } uu; uu.h = (f16)hv;
            __hip_atomic_store(hw + (q * 4 + r) * 8, uu.s2, __ATOMIC_RELAXED, __HIP_MEMORY_SCOPE_AGENT);
            if (WZ && t == 99) zw[(q * 4 + r) * 8] = uu.h;   // plain store; kernel boundary before dec
        }
        if (l == 0)
            __hip_atomic_fetch_add(flc + t, 1, __ATOMIC_RELEASE, __HIP_MEMORY_SCOPE_AGENT);
    }
}

// Fused decoder: dec0 (xz const over t, in regs) + dec1 + out-proj. 64 blocks x 256 thr.
__global__ __launch_bounds__(256, 1) void lstm_dec_kernel(
    const f16* __restrict__ zbuf,
    const f16* __restrict__ pkD0i, const f16* __restrict__ pkD0h,
    const f16* __restrict__ pkD1,  const f16* __restrict__ pkOut,
    const float* __restrict__ bd0, const float* __restrict__ bd1,
    const float* __restrict__ out_b, float* __restrict__ out)
{
    constexpr int T = 100;
    __shared__ __align__(16) f16 hdfrag[4 * 64 * 8];
    int tid = threadIdx.x;
    int l = tid & 63, w = tid >> 6;
    int p = l & 15, q = l >> 4;
    int c = blockIdx.x;
    int b0 = c * 16;

    for (int i = tid; i < 2048; i += 256) hdfrag[i] = (f16)0.f;

    f16x8 wd0[4][2], wd1[4][4], wo[4][2];
    #pragma unroll
    for (int g = 0; g < 4; ++g) {
        #pragma unroll
        for (int kt = 0; kt < 2; ++kt) wd0[g][kt] = ((const f16x8*)pkD0h)[(long)(((g * 4 + w) * 2 + kt)) * 64 + l];
        #pragma unroll
        for (int kt = 0; kt < 4; ++kt) wd1[g][kt] = ((const f16x8*)pkD1)[(long)(((g * 4 + w) * 4 + kt)) * 64 + l];
        #pragma unroll
        for (int kt = 0; kt < 2; ++kt) wo[g][kt]  = ((const f16x8*)pkOut)[(long)(((w * 4 + g) * 2 + kt)) * 64 + l];
    }

    // xz = z @ dW0i^T + bd0 (z = h1_99 from zbuf, A-frag layout)
    f32x4 xz[4];
    #pragma unroll
    for (int g = 0; g < 4; ++g) xz[g] = (f32x4){0.f, 0.f, 0.f, 0.f};
    {
        const f16x8* zp = (const f16x8*)zbuf + (long)(c * 8) * 64 + l;
        const f16x8* wp = (const f16x8*)pkD0i + l;
        #pragma unroll
        for (int kt = 0; kt < 8; ++kt) {
            f16x8 a = zp[kt * 64];
            #pragma unroll
            for (int g = 0; g < 4; ++g)
                xz[g] = MFMA16(a, wp[((g * 4 + w) * 8 + kt) * 64], xz[g]);
        }
        #pragma unroll
        for (int g = 0; g < 4; ++g) {
            float bb = bd0[g * 64 + w * 16 + p];
            #pragma unroll
            for (int r = 0; r < 4; ++r) xz[g][r] += bb;
        }
    }
    float bs1[4], bso[4];
    #pragma unroll
    for (int g = 0; g < 4; ++g) bs1[g] = bd1[g * 64 + w * 16 + p];
    #pragma unroll
    for (int i = 0; i < 4; ++i) bso[i] = out_b[(w * 4 + i) * 16 + p];
    float c0[4] = {0.f, 0.f, 0.f, 0.f}, c1[4] = {0.f, 0.f, 0.f, 0.f};
    __syncthreads();

    for (int t = 0; t < T; ++t) {
        f32x4 acc[4];
        #pragma unroll
        for (int g = 0; g < 4; ++g) acc[g] = (f32x4){0.f, 0.f, 0.f, 0.f};
        #pragma unroll
        for (int kt = 0; kt < 2; ++kt) {
            f16x8 a = *(const f16x8*)&hdfrag[(kt * 64 + l) * 8];
            #pragma unroll
            for (int g = 0; g < 4; ++g)
                acc[g] = MFMA16(a, wd0[g][kt], acc[g]);
        }
        __syncthreads();
        #pragma unroll
        for (int r = 0; r < 4; ++r) {
            float iv = sigmoidf_(acc[0][r] + xz[0][r]);
            float fv = sigmoidf_(acc[1][r] + xz[1][r]);
            float gv = tanhf_(acc[2][r] + xz[2][r]);
            float ov = sigmoidf_(acc[3][r] + xz[3][r]);
            float cv = fv * c0[r] + iv * gv; c0[r] = cv;
            float hv = ov * tanhf_(cv);
            int j = w * 16 + p, b = q * 4 + r;
            hdfrag[((j >> 5) * 64 + ((j >> 3) & 3) * 16 + b) * 8 + (j & 7)] = (f16)hv;
        }
        __syncthreads();
        f32x4 acc1[4];
        #pragma unroll
        for (int g = 0; g < 4; ++g) acc1[g] = (f32x4){0.f, 0.f, 0.f, 0.f};
        #pragma unroll
        for (int kt = 0; kt < 4; ++kt) {
            f16x8 a = *(const f16x8*)&hdfrag[(kt * 64 + l) * 8];
            #pragma unroll
            for (int g = 0; g < 4; ++g)
                acc1[g] = MFMA16(a, wd1[g][kt], acc1[g]);
        }
        __syncthreads();
        #pragma unroll
        for (int r = 0; r < 4; ++r) {
            float iv = sigmoidf_(acc1[0][r] + bs1[0]);
            float fv = sigmoidf_(acc1[1][r] + bs1[1]);
            float gv = tanhf_(acc1[2][r] + bs1[2]);
            float ov = sigmoidf_(acc1[3][r] + bs1[3]);
            float cv = fv * c1[r] + iv * gv; c1[r] = cv;
            float hv = ov * tanhf_(cv);
            int j = w * 16 + p, b = q * 4 + r;
            int k = 64 + j;
            hdfrag[((k >> 5) * 64 + ((k >> 3) & 3) * 16 + b) * 8 + (k & 7)] = (f16)hv;
        }
        __syncthreads();
        f32x4 acco[4];
        #pragma unroll
        for (int i = 0; i < 4; ++i) acco[i] = (f32x4){0.f, 0.f, 0.f, 0.f};
        #pragma unroll
        for (int kt = 0; kt < 2; ++kt) {
            f16x8 a = *(const f16x8*)&hdfrag[((2 + kt) * 64 + l) * 8];
            #pragma unroll
            for (int i = 0; i < 4; ++i)
                acco[i] = MFMA16(a, wo[i][kt], acco[i]);
        }
        #pragma unroll
        for (int i = 0; i < 4; ++i)
            #pragma unroll
            for (int r = 0; r < 4; ++r)
                out[((long)(b0 + q * 4 + r) * T + t) * 256 + (w * 4 + i) * 16 + p] = acco[i][r] + bso[i];
    }
}

extern "C" void kernel_launch(void* const* d_in, const int* in_sizes, int n_in,
                              void* d_out, int out_size, void* d_ws, size_t ws_size,
                              hipStream_t stream)
{
    const float* x    = (const float*)d_in[0];
    const float* inW  = (const float*)d_in[1];
    const float* inb  = (const float*)d_in[2];
    const float* e0i  = (const float*)d_in[3];
    const float* e0h  = (const float*)d_in[4];
    const float* eb0i = (const float*)d_in[5];
    const float* eb0h = (const float*)d_in[6];
    const float* e1i  = (const float*)d_in[7];
    const float* e1h  = (const float*)d_in[8];
    const float* eb1i = (const float*)d_in[9];
    const float* eb1h = (const float*)d_in[10];
    const float* d0i  = (const float*)d_in[11];
    const float* d0h  = (const float*)d_in[12];
    const float* db0i = (const float*)d_in[13];
    const float* db0h = (const float*)d_in[14];
    const float* d1i  = (const float*)d_in[15];
    const float* d1h  = (const float*)d_in[16];
    const float* db1i = (const float*)d_in[17];
    const float* db1h = (const float*)d_in[18];
    const float* outW = (const float*)d_in[19];
    const float* outb = (const float*)d_in[20];

    char* ws = (char*)d_ws;
    f16*   pk     = (f16*)ws;
    float* biases = (float*)(ws + BIAS_OFF);
    int*   flags0 = (int*)(ws + FLAGS_OFF);
    int*   flags1 = flags0 + 6400;
    f16*   h0x    = (f16*)(ws + H0X_OFF);
    f16*   hx1    = (f16*)(ws + HX1_OFF);
    f16*   zbuf   = (f16*)(ws + ZB_OFF);
    f16*   h1x    = (f16*)(ws + H1X_OFF);
    float* out    = (float*)d_out;

    init_flags<<<50, 256, 0, stream>>>(flags0);
    pack_kernel<<<498, 256, 0, stream>>>(inW, e0i, e0h, e1i, e1h, d0i, d0h, d1i, d1h, outW,
                                         eb0i, eb0h, eb1i, eb1h, db0i, db0h, db1i, db1h,
                                         pk, biases);
    inproj_kernel<<<6400, 256, 0, stream>>>(x, pk, inb, h0x);

    lstm_enc_reg<2, 100, false><<<256, 256, 0, stream>>>(h0x, pk + 16384, biases, h1x, flags0, zbuf);
    lstm_enc_reg<8, 4,   true ><<<256, 256, 0, stream>>>(h1x, pk + 344064, biases + 1024, hx1, flags1, zbuf);
    lstm_dec_kernel<<<64, 256, 0, stream>>>(zbuf, pk + 868352, pk + 933888, pk + 950272, pk + 983040,
                                            biases + 2048, biases + 2304, outb, out);
}